// Round 7
// baseline (95.141 us; speedup 1.0000x reference)
//
#include <hip/hip_runtime.h>

// GAM forward: 64 per-feature MLPs 1->16->16->16->1 (ELU), pred = out@Wp+bp.
// R1: row-major lane=sample access -> 250x RMW blowup. Fixed: transposed ws.
// R2/R5: pointer-cast local arrays -> scratch spill. Fixed: reg-friendly state.
// R6: LDS eliminated via wave-uniform s_load weights -> 82us, VALUBusy 79%,
//   VALU-ISSUE-bound (FMA issue floor 29us + ELU ~20us).
// R7: halve FMA issue with v_pk_fma_f32: state = sample-pairs in float2
//   (ext_vector v2f); __builtin_elementwise_fma on v2f selects VOP3P packed
//   fp32 on gfx90a+. SPT=4 (2 pairs) amortizes the {w,w} splat. ELU as
//   max(v,0)+min(exp(v)-1,0): bit-identical, pk-friendly (exp stays scalar).

#define BLK 256
#define FGF 4       // features per block (fast path)
#define FG 8        // features per block (fallback path)
#define DTOT 64

typedef float v2f __attribute__((ext_vector_type(2)));

__device__ __forceinline__ v2f mul2(float s, v2f v) {
    v2f w = {s, s};
    return w * v;                       // v_pk_mul_f32
}
__device__ __forceinline__ v2f fma2(float s, v2f h, v2f a) {
    v2f w = {s, s};
    return __builtin_elementwise_fma(w, h, a);   // v_pk_fma_f32
}
__device__ __forceinline__ v2f elu2(v2f v) {
    // elu(v) = max(v,0) + min(exp(v)-1, 0)  (bit-identical to select form)
    v2f e;
    e.x = __expf(v.x);
    e.y = __expf(v.y);
    const v2f zero = {0.f, 0.f};
    const v2f one  = {1.f, 1.f};
    return __builtin_elementwise_max(v, zero) +
           __builtin_elementwise_min(e - one, zero);
}

__device__ __forceinline__ float elu_f(float v) {
    return v > 0.0f ? v : (__expf(v) - 1.0f);
}
__device__ __forceinline__ float4 mul4(float s, float4 w) {
    float4 r;
    r.x = s * w.x; r.y = s * w.y; r.z = s * w.z; r.w = s * w.w;
    return r;
}
__device__ __forceinline__ float4 fma4(float s, float4 w, float4 a) {
    a.x = fmaf(s, w.x, a.x); a.y = fmaf(s, w.y, a.y);
    a.z = fmaf(s, w.z, a.z); a.w = fmaf(s, w.w, a.w);
    return a;
}
__device__ __forceinline__ float4 elu4(float4 v) {
    float4 r;
    r.x = elu_f(v.x); r.y = elu_f(v.y); r.z = elu_f(v.z); r.w = elu_f(v.w);
    return r;
}
__device__ __forceinline__ float dot4(float4 a, float4 b) {
    return fmaf(a.x, b.x, fmaf(a.y, b.y, fmaf(a.z, b.z, a.w * b.w)));
}
__device__ __forceinline__ float4 zero4() {
    float4 r; r.x = 0.f; r.y = 0.f; r.z = 0.f; r.w = 0.f; return r;
}
__device__ __forceinline__ float getc(float4 v, int i) {
    switch (i & 3) {
        case 0: return v.x;
        case 1: return v.y;
        case 2: return v.z;
        default: return v.w;
    }
}
#define GET16(h0, h1, h2, h3, i) \
    getc((i) < 4 ? (h0) : (i) < 8 ? (h1) : (i) < 12 ? (h2) : (h3), (i))

// ---------------- fast path: transposed domain, SMEM weights, pk math -----

// x (N,64) -> xt (64,N). 64x64 tiles via LDS (pad 65 -> conflict-free).
__global__ __launch_bounds__(256) void transpose_in(
    const float* __restrict__ x, float* __restrict__ xt, int nsamp)
{
    __shared__ float t[64][65];
    const int s0 = blockIdx.x * 64;
    const int c = threadIdx.x & 63;
    const int r0 = threadIdx.x >> 6;
    for (int i = r0; i < 64; i += 4)
        t[i][c] = x[(size_t)(s0 + i) * DTOT + c];
    __syncthreads();
    for (int d = r0; d < 64; d += 4)
        xt[(size_t)d * nsamp + s0 + c] = t[c][d];
}

// SPT=4 as two sample-pairs (v2f). No LDS, weights via uniform s_load.
// Spill-tell for next round: VGPR anomalously low + WRITE_SIZE blowup.
__global__ __launch_bounds__(BLK) void gam_main_p(
    const float* __restrict__ xt, const float* __restrict__ W1,
    const float* __restrict__ W2, const float* __restrict__ W3,
    const float* __restrict__ W4, float* __restrict__ ot, int nsamp)
{
    const int tid = threadIdx.x;
    const int g = blockIdx.x & 15;       // feature group (16 groups of 4)
    const int chunk = blockIdx.x >> 4;   // sample chunk (1024 samples)
    const int d0 = g * FGF;

    const int s0 = chunk * (BLK * 4) + tid;
    if (s0 >= nsamp) return;

#pragma unroll 1
    for (int dd = 0; dd < FGF; ++dd) {
        const int d = d0 + dd;
        const size_t rowb = (size_t)d * nsamp;

        // pair A = samples {s0, s0+BLK}; pair B = {s0+2BLK, s0+3BLK}
        v2f xA, xB;
        xA.x = xt[rowb + s0];
        xA.y = xt[rowb + s0 + BLK];
        xB.x = xt[rowb + s0 + 2 * BLK];
        xB.y = xt[rowb + s0 + 3 * BLK];

        // uniform per-feature weight bases (SALU arithmetic -> s_load)
        const float* w1p = W1 + (size_t)d * 1024 + d * 16;
        const float* w2p = W2 + (size_t)d * 16 * 1024 + d * 16;
        const float* w3p = W3 + (size_t)d * 16 * 1024 + d * 16;

        v2f hA[16], hB[16];
        // layer 1: h = elu(x * w1_j)
#pragma unroll
        for (int j = 0; j < 16; ++j) {
            const float w = w1p[j];
            hA[j] = elu2(mul2(w, xA));
            hB[j] = elu2(mul2(w, xB));
        }

        // layer 2: acc_j = sum_i w[i][j] * h_i (i-sequential, same assoc)
        {
            v2f aA[16], aB[16];
#pragma unroll
            for (int j = 0; j < 16; ++j) { aA[j] = (v2f){0.f, 0.f}; aB[j] = (v2f){0.f, 0.f}; }
#pragma unroll
            for (int i = 0; i < 16; ++i) {
                const float* wr = w2p + (size_t)i * 1024;
                const v2f hAi = hA[i], hBi = hB[i];
#pragma unroll
                for (int j = 0; j < 16; ++j) {
                    const float w = wr[j];
                    aA[j] = fma2(w, hAi, aA[j]);
                    aB[j] = fma2(w, hBi, aB[j]);
                }
            }
#pragma unroll
            for (int j = 0; j < 16; ++j) { hA[j] = elu2(aA[j]); hB[j] = elu2(aB[j]); }
        }

        // layer 3
        {
            v2f aA[16], aB[16];
#pragma unroll
            for (int j = 0; j < 16; ++j) { aA[j] = (v2f){0.f, 0.f}; aB[j] = (v2f){0.f, 0.f}; }
#pragma unroll
            for (int i = 0; i < 16; ++i) {
                const float* wr = w3p + (size_t)i * 1024;
                const v2f hAi = hA[i], hBi = hB[i];
#pragma unroll
                for (int j = 0; j < 16; ++j) {
                    const float w = wr[j];
                    aA[j] = fma2(w, hAi, aA[j]);
                    aB[j] = fma2(w, hBi, aB[j]);
                }
            }
#pragma unroll
            for (int j = 0; j < 16; ++j) { hA[j] = elu2(aA[j]); hB[j] = elu2(aB[j]); }
        }

        // layer 4: two stride-2 partial chains (matches R6 association)
        v2f oA0 = {0.f, 0.f}, oA1 = {0.f, 0.f};
        v2f oB0 = {0.f, 0.f}, oB1 = {0.f, 0.f};
#pragma unroll
        for (int i = 0; i < 16; i += 2) {
            const float wa = W4[(size_t)(d * 16 + i) * 64 + d];
            const float wb = W4[(size_t)(d * 16 + i + 1) * 64 + d];
            oA0 = fma2(wa, hA[i], oA0);
            oB0 = fma2(wa, hB[i], oB0);
            oA1 = fma2(wb, hA[i + 1], oA1);
            oB1 = fma2(wb, hB[i + 1], oB1);
        }
        const v2f oA = oA0 + oA1, oB = oB0 + oB1;
        ot[rowb + s0]           = oA.x;   // lane-contiguous stores
        ot[rowb + s0 + BLK]     = oA.y;
        ot[rowb + s0 + 2 * BLK] = oB.x;
        ot[rowb + s0 + 3 * BLK] = oB.y;
    }
}

// ot (64,N) -> out (N,64) AND pred[s] = bp + sum_d ot[d][s]*Wp[d], fused.
__global__ __launch_bounds__(256) void finish(
    const float* __restrict__ ot, const float* __restrict__ Wp,
    const float* __restrict__ bp, float* __restrict__ out,
    float* __restrict__ pred, int nsamp)
{
    __shared__ float t[64][65];
    __shared__ float wps[64];
    const int s0 = blockIdx.x * 64;
    const int c = threadIdx.x & 63;
    const int r0 = threadIdx.x >> 6;
    if (threadIdx.x < 64) wps[threadIdx.x] = Wp[threadIdx.x];
    for (int d = r0; d < 64; d += 4)
        t[d][c] = ot[(size_t)d * nsamp + s0 + c];
    __syncthreads();
    for (int i = r0; i < 64; i += 4)
        out[(size_t)(s0 + i) * DTOT + c] = t[c][i];   // full 256B lines
    if (r0 == 0) {
        float p = bp[0];
#pragma unroll
        for (int d = 0; d < 64; ++d)
            p = fmaf(t[d][c], wps[d], p);   // banks (d+c)%32: conflict-free
        pred[s0 + c] = p;
    }
}

// ---------------- fallback (ws too small; LDS-staged, strided I/O) --------

__device__ __forceinline__ void stage_weights(
    int tid, int d0,
    const float* __restrict__ W1, const float* __restrict__ W2,
    const float* __restrict__ W3, const float* __restrict__ W4,
    float (*w1s)[16], float (*w2s)[16][16], float (*w3s)[16][16], float (*w4s)[16])
{
    if (tid < 128) {
        int dd = tid >> 4, j = tid & 15;
        int d = d0 + dd;
        w1s[dd][j] = W1[d * 1024 + d * 16 + j];
    } else {
        int t = tid - 128;
        int dd = t >> 4, i = t & 15;
        int d = d0 + dd;
        w4s[dd][i] = W4[(d * 16 + i) * 64 + d];
    }
    for (int idx = tid; idx < FG * 256; idx += BLK) {
        int dd = idx >> 8, r = idx & 255;
        int i = r >> 4, j = r & 15;
        int d = d0 + dd;
        size_t base = (size_t)(d * 16 + i) * 1024 + d * 16 + j;
        w2s[dd][i][j] = W2[base];
        w3s[dd][i][j] = W3[base];
    }
}

#define LAYER16L(ws)                                                       \
    {                                                                      \
        float4 a0 = zero4(), a1 = zero4(), a2 = zero4(), a3 = zero4();     \
        float4 b0 = zero4(), b1 = zero4(), b2 = zero4(), b3 = zero4();     \
        _Pragma("unroll")                                                  \
        for (int i = 0; i < 16; ++i) {                                     \
            const float hai = GET16(ha0, ha1, ha2, ha3, i);                \
            const float hbi = GET16(hb0, hb1, hb2, hb3, i);                \
            const float4* wp = (const float4*)((ws) + i * 16);             \
            const float4 q0 = wp[0], q1 = wp[1], q2 = wp[2], q3 = wp[3];   \
            a0 = fma4(hai, q0, a0); a1 = fma4(hai, q1, a1);                \
            a2 = fma4(hai, q2, a2); a3 = fma4(hai, q3, a3);                \
            b0 = fma4(hbi, q0, b0); b1 = fma4(hbi, q1, b1);                \
            b2 = fma4(hbi, q2, b2); b3 = fma4(hbi, q3, b3);                \
        }                                                                  \
        ha0 = elu4(a0); ha1 = elu4(a1); ha2 = elu4(a2); ha3 = elu4(a3);    \
        hb0 = elu4(b0); hb1 = elu4(b1); hb2 = elu4(b2); hb3 = elu4(b3);    \
    }

__global__ __launch_bounds__(BLK, 4) void gam_main_direct(
    const float* __restrict__ x, const float* __restrict__ W1,
    const float* __restrict__ W2, const float* __restrict__ W3,
    const float* __restrict__ W4, float* __restrict__ out, int nsamp)
{
    __shared__ float w1s[FG][16];
    __shared__ float w2s[FG][16][16];
    __shared__ float w3s[FG][16][16];
    __shared__ float w4s[FG][16];

    const int tid = threadIdx.x;
    const int g = blockIdx.x & 7;
    const int chunk = blockIdx.x >> 3;
    const int d0 = g * FG;

    stage_weights(tid, d0, W1, W2, W3, W4, w1s, w2s, w3s, w4s);
    __syncthreads();

    const int s0 = chunk * (BLK * 2) + tid;
    const int s1 = s0 + BLK;
    if (s0 >= nsamp) return;

    for (int dd = 0; dd < FG; ++dd) {
        const int d = d0 + dd;
        const float xv0 = x[(size_t)s0 * DTOT + d];
        const float xv1 = x[(size_t)s1 * DTOT + d];

        const float4* w1p = (const float4*)&w1s[dd][0];
        const float4 u0 = w1p[0], u1 = w1p[1], u2 = w1p[2], u3 = w1p[3];
        float4 ha0 = elu4(mul4(xv0, u0)), ha1 = elu4(mul4(xv0, u1));
        float4 ha2 = elu4(mul4(xv0, u2)), ha3 = elu4(mul4(xv0, u3));
        float4 hb0 = elu4(mul4(xv1, u0)), hb1 = elu4(mul4(xv1, u1));
        float4 hb2 = elu4(mul4(xv1, u2)), hb3 = elu4(mul4(xv1, u3));

        LAYER16L(&w2s[dd][0][0]);
        LAYER16L(&w3s[dd][0][0]);

        const float4* w4p = (const float4*)&w4s[dd][0];
        const float4 q0 = w4p[0], q1 = w4p[1], q2 = w4p[2], q3 = w4p[3];
        out[(size_t)s0 * DTOT + d] = (dot4(ha0, q0) + dot4(ha1, q1)) +
                                     (dot4(ha2, q2) + dot4(ha3, q3));
        out[(size_t)s1 * DTOT + d] = (dot4(hb0, q0) + dot4(hb1, q1)) +
                                     (dot4(hb2, q2) + dot4(hb3, q3));
    }
}

__global__ __launch_bounds__(BLK) void gam_pred_direct(
    const float* __restrict__ out, const float* __restrict__ Wp,
    const float* __restrict__ bp, float* __restrict__ pred, int nsamp)
{
    int gid = blockIdx.x * BLK + threadIdx.x;
    int wave = gid >> 6, lane = gid & 63;
    int sub = lane >> 4, li = lane & 15;
    int s = wave * 4 + sub;
    if (s >= nsamp) return;
    float4 wv = ((const float4*)Wp)[li];
    float4 v = ((const float4*)(out + (size_t)s * DTOT))[li];
    float p = v.x * wv.x + v.y * wv.y + v.z * wv.z + v.w * wv.w;
    p += __shfl_xor(p, 1);
    p += __shfl_xor(p, 2);
    p += __shfl_xor(p, 4);
    p += __shfl_xor(p, 8);
    if (li == 0) pred[s] = p + bp[0];
}

extern "C" void kernel_launch(void* const* d_in, const int* in_sizes, int n_in,
                              void* d_out, int out_size, void* d_ws, size_t ws_size,
                              hipStream_t stream) {
    const float* x  = (const float*)d_in[0];
    const float* W1 = (const float*)d_in[1];
    const float* W2 = (const float*)d_in[2];
    const float* W3 = (const float*)d_in[3];
    const float* W4 = (const float*)d_in[4];
    const float* Wp = (const float*)d_in[5];
    const float* bp = (const float*)d_in[6];

    const int nsamp = in_sizes[0] / DTOT;   // 65536
    float* pred = (float*)d_out;            // (N,1) first
    float* outm = pred + nsamp;             // (N,64) second

    const size_t need = (size_t)2 * nsamp * DTOT * sizeof(float);
    if (ws_size >= need && (nsamp % (BLK * 4)) == 0) {
        float* xt = (float*)d_ws;
        float* ot = xt + (size_t)nsamp * DTOT;
        transpose_in<<<dim3(nsamp / 64), dim3(256), 0, stream>>>(x, xt, nsamp);
        // nsamp/1024 chunks x 16 groups (FGF=4)
        gam_main_p<<<dim3((nsamp / (BLK * 4)) * 16), dim3(BLK), 0, stream>>>(
            xt, W1, W2, W3, W4, ot, nsamp);
        finish<<<dim3(nsamp / 64), dim3(256), 0, stream>>>(
            ot, Wp, bp, outm, pred, nsamp);
    } else {
        int chunks = nsamp / (BLK * 2);
        gam_main_direct<<<dim3(chunks * 8), dim3(BLK), 0, stream>>>(
            x, W1, W2, W3, W4, outm, nsamp);
        int nthreads = (nsamp / 4) * 64;
        gam_pred_direct<<<dim3((nthreads + BLK - 1) / BLK), dim3(BLK), 0, stream>>>(
            outm, Wp, bp, pred, nsamp);
    }
}